// Round 1
// baseline (184.128 us; speedup 1.0000x reference)
//
#include <hip/hip_runtime.h>

// Problem constants
// B=16, C=64, P=128, L=16, D=256, NPF=256, NRFF=128 (64 sin + 64 cos), FEAT=656
// ws layout (floats):
#define WS_WK0   0        // 16
#define WS_A     16       // 256   A = Wq1^T Wk1
#define WS_E0    272      // 4096  E0 = Pp0 * Wv0   (256 x 16)
#define WS_E1    4368     // 4096  E1 = Pp1 * Wv1   (256 x 16)
#define WS_PT    8464     // 32768 PrffT: [j][0..255]=sin-w, [j][256..511]=cos-w
// total 41232 floats = 165 KB

#define XST_LD 68   // padded leading dim for X^T in LDS (bank-conflict avoidance)

__global__ __launch_bounds__(512)
void pre_kernel(const float* __restrict__ Wq, const float* __restrict__ Wk,
                const float* __restrict__ Wv, const float* __restrict__ pw,
                float* __restrict__ ws)
{
  __shared__ float q0s[256];
  const int t = threadIdx.x;
  const int blk = blockIdx.x;
  if (blk == 0) {
    if (t < 256) {
      float s = 0.f;
      #pragma unroll
      for (int l = 0; l < 16; ++l) s += Wq[t*16 + l];   // q0[d] = sum_l Wq0[d,l]
      q0s[t] = s;
    }
    __syncthreads();
    if (t < 16) {
      float s = 0.f;
      for (int d = 0; d < 256; ++d) s += q0s[d] * Wk[d*16 + t];  // wk0[l]
      ws[WS_WK0 + t] = s;
    }
    if (t < 256) {
      const int l1 = t >> 4, l2 = t & 15;
      float s = 0.f;
      for (int d = 0; d < 256; ++d)
        s += Wq[4096 + d*16 + l1] * Wk[4096 + d*16 + l2];  // A[l1,l2]
      ws[WS_A + t] = s;
    }
  } else if (blk <= 8) {
    const int d = (blk-1)*32 + (t >> 4);
    const int l = t & 15;
    float s = 0.f;
    for (int f = 0; f < 256; ++f) s += pw[d*656 + 16 + f] * Wv[f*16 + l];
    ws[WS_E0 + d*16 + l] = s;
  } else if (blk <= 16) {
    const int d = (blk-9)*32 + (t >> 4);
    const int l = t & 15;
    float s = 0.f;
    for (int f = 0; f < 256; ++f) s += pw[d*656 + 272 + f] * Wv[4096 + f*16 + l];
    ws[WS_E1 + d*16 + l] = s;
  } else {
    // transpose Prff (sin block cols 528..591, cos block 592..655) to [j][512]
    const int base = (blk - 17) * 8192;
    #pragma unroll
    for (int k = 0; k < 16; ++k) {
      const int e = base + k*512 + t;
      const int j = e >> 9;
      const int col = e & 511;
      const float v = (col < 256) ? pw[col*656 + 528 + j]
                                  : pw[(col-256)*656 + 592 + j];
      ws[WS_PT + e] = v;
    }
  }
}

__global__ __launch_bounds__(256, 2)
void main_kernel(const float* __restrict__ x, const float* __restrict__ fw,
                 const float* __restrict__ fb, const float* __restrict__ pw,
                 const float* __restrict__ pb, const float* __restrict__ ws,
                 float* __restrict__ out)
{
  __shared__ float XsT[16*XST_LD];  // X^T: [l][c], padded
  __shared__ float fws[16*64];
  __shared__ float fbs[64];
  __shared__ float Gs[256];         // G = X^T X
  __shared__ float N1s[256];        // N1 = A*G
  __shared__ float tls[16];         // t = G*wk0
  __shared__ float c0s[256];        // pb[d] + sum_l t[l]*E0[d,l]
  __shared__ float Weff[16*256];    // [l'][d] = Px[d,l'] + sum_l N1[l',l]E1[d,l]
  __shared__ float sjs[64*64];      // sin(wx)[j][c]
  __shared__ float cjs[64*64];      // cos(wx)[j][c]

  const int t = threadIdx.x;
  const int b = blockIdx.x >> 7;
  const int p = blockIdx.x & 127;

  // ---- stage X^T (one (b,p) slice: 64 channels x 16 lags) ----
  {
    const int c = t >> 2, l0 = (t & 3) * 4;
    const float4 v = *(const float4*)(x + (((b*64 + c)*128 + p) << 4) + l0);
    XsT[(l0+0)*XST_LD + c] = v.x;
    XsT[(l0+1)*XST_LD + c] = v.y;
    XsT[(l0+2)*XST_LD + c] = v.z;
    XsT[(l0+3)*XST_LD + c] = v.w;
  }
  *(float4*)(fws + t*4) = *(const float4*)(fw + t*4);
  if (t < 16) *(float4*)(fbs + t*4) = *(const float4*)(fb + t*4);
  __syncthreads();

  // ---- G[l1][l2] = sum_c X[c,l1]X[c,l2] ----
  {
    const int l1 = t >> 4, l2 = t & 15;
    float g = 0.f;
    #pragma unroll
    for (int c = 0; c < 64; ++c) g += XsT[l1*XST_LD + c] * XsT[l2*XST_LD + c];
    Gs[t] = g;
  }
  // ---- wx + sincos table: thread owns channel c, 16 of the 64 freqs ----
  {
    const int c = t & 63, jb = t >> 6;
    #pragma unroll
    for (int k = 0; k < 16; ++k) {
      const int j = jb*16 + k;
      float wx = fbs[j];
      #pragma unroll
      for (int l = 0; l < 16; ++l) wx += XsT[l*XST_LD + c] * fws[l*64 + j];
      float sv, cv;
      __sincosf(wx, &sv, &cv);
      sjs[j*64 + c] = sv;
      cjs[j*64 + c] = cv;
    }
  }
  __syncthreads();

  // ---- N1 = A*G ; tls = G*wk0 ----
  {
    const int l1 = t >> 4, l2 = t & 15;
    float s = 0.f;
    #pragma unroll
    for (int k = 0; k < 16; ++k) s += ws[WS_A + l1*16 + k] * Gs[k*16 + l2];
    N1s[t] = s;
  }
  if (t < 16) {
    float s = 0.f;
    #pragma unroll
    for (int k = 0; k < 16; ++k) s += Gs[t*16 + k] * ws[WS_WK0 + k];
    tls[t] = s;
  }
  __syncthreads();

  // ---- W_eff[l'][d] and c0[d]  (thread == d) ----
  {
    const int d = t;
    float e1r[16], pxr[16], e0r[16];
    #pragma unroll
    for (int q = 0; q < 4; ++q) {
      *(float4*)(e1r + q*4) = *(const float4*)(ws + WS_E1 + d*16 + q*4);
      *(float4*)(e0r + q*4) = *(const float4*)(ws + WS_E0 + d*16 + q*4);
      *(float4*)(pxr + q*4) = *(const float4*)(pw + d*656 + q*4);
    }
    #pragma unroll
    for (int lp = 0; lp < 16; ++lp) {
      float s = pxr[lp];
      #pragma unroll
      for (int l = 0; l < 16; ++l) s += N1s[lp*16 + l] * e1r[l];
      Weff[lp*256 + d] = s;
    }
    float s = pb[d];
    #pragma unroll
    for (int l = 0; l < 16; ++l) s += tls[l] * e0r[l];
    c0s[d] = s;
  }
  __syncthreads();

  // ---- 8c x 8d register-tiled accumulation ----
  const int cg = t & 7;    // c-tile: cg*8 .. cg*8+7
  const int dg = t >> 3;   // d-tile: dg*8 .. dg*8+7
  float acc[8][8];
  {
    const float4 c00 = *(const float4*)(c0s + dg*8);
    const float4 c01 = *(const float4*)(c0s + dg*8 + 4);
    const float cc[8] = {c00.x,c00.y,c00.z,c00.w,c01.x,c01.y,c01.z,c01.w};
    #pragma unroll
    for (int i = 0; i < 8; ++i)
      #pragma unroll
      for (int k = 0; k < 8; ++k) acc[i][k] = cc[k];
  }
  #pragma unroll
  for (int lp = 0; lp < 16; ++lp) {
    const float4 x0 = *(const float4*)(XsT + lp*XST_LD + cg*8);
    const float4 x1 = *(const float4*)(XsT + lp*XST_LD + cg*8 + 4);
    const float4 w0 = *(const float4*)(Weff + lp*256 + dg*8);
    const float4 w1 = *(const float4*)(Weff + lp*256 + dg*8 + 4);
    const float xv[8] = {x0.x,x0.y,x0.z,x0.w,x1.x,x1.y,x1.z,x1.w};
    const float wv[8] = {w0.x,w0.y,w0.z,w0.w,w1.x,w1.y,w1.z,w1.w};
    #pragma unroll
    for (int i = 0; i < 8; ++i)
      #pragma unroll
      for (int k = 0; k < 8; ++k) acc[i][k] += xv[i] * wv[k];
  }
  const float* PT = ws + WS_PT;
  #pragma unroll 2
  for (int j = 0; j < 64; ++j) {
    const float4 s0 = *(const float4*)(sjs + j*64 + cg*8);
    const float4 s1 = *(const float4*)(sjs + j*64 + cg*8 + 4);
    const float4 q0 = *(const float4*)(cjs + j*64 + cg*8);
    const float4 q1 = *(const float4*)(cjs + j*64 + cg*8 + 4);
    const float4 ps0 = *(const float4*)(PT + j*512 + dg*8);
    const float4 ps1 = *(const float4*)(PT + j*512 + dg*8 + 4);
    const float4 pc0 = *(const float4*)(PT + j*512 + 256 + dg*8);
    const float4 pc1 = *(const float4*)(PT + j*512 + 256 + dg*8 + 4);
    const float sv[8] = {s0.x,s0.y,s0.z,s0.w,s1.x,s1.y,s1.z,s1.w};
    const float cv[8] = {q0.x,q0.y,q0.z,q0.w,q1.x,q1.y,q1.z,q1.w};
    const float pv[8] = {ps0.x,ps0.y,ps0.z,ps0.w,ps1.x,ps1.y,ps1.z,ps1.w};
    const float qv[8] = {pc0.x,pc0.y,pc0.z,pc0.w,pc1.x,pc1.y,pc1.z,pc1.w};
    #pragma unroll
    for (int i = 0; i < 8; ++i)
      #pragma unroll
      for (int k = 0; k < 8; ++k)
        acc[i][k] += sv[i]*pv[k] + cv[i]*qv[k];
  }
  // ---- store ----
  #pragma unroll
  for (int i = 0; i < 8; ++i) {
    const int c = cg*8 + i;
    float* o = out + (((b*64 + c)*128 + p) << 8) + dg*8;
    const float4 v0 = make_float4(acc[i][0], acc[i][1], acc[i][2], acc[i][3]);
    const float4 v1 = make_float4(acc[i][4], acc[i][5], acc[i][6], acc[i][7]);
    *(float4*)(o) = v0;
    *(float4*)(o + 4) = v1;
  }
}

extern "C" void kernel_launch(void* const* d_in, const int* in_sizes, int n_in,
                              void* d_out, int out_size, void* d_ws, size_t ws_size,
                              hipStream_t stream) {
  const float* x  = (const float*)d_in[0];
  const float* Wq = (const float*)d_in[1];
  const float* Wk = (const float*)d_in[2];
  const float* Wv = (const float*)d_in[3];
  const float* fw = (const float*)d_in[4];
  const float* fb = (const float*)d_in[5];
  const float* pw = (const float*)d_in[6];
  const float* pb = (const float*)d_in[7];
  float* out = (float*)d_out;
  float* ws  = (float*)d_ws;   // needs 41232 floats = 165 KB

  pre_kernel<<<21, 512, 0, stream>>>(Wq, Wk, Wv, pw, ws);
  main_kernel<<<16*128, 256, 0, stream>>>(x, fw, fb, pw, pb, ws, out);
}

// Round 3
// 53.507 us; speedup vs baseline: 3.4412x; 3.4412x over previous
//
#include <hip/hip_runtime.h>
#include <hip/hip_bf16.h>

// B=16, C=64, P=128, L=16, D=256, NPF=256, NRFF=128, FEAT=656
// ws layout (float slots):
#define WS_WK0   0        // 16     wk0 = Wk0^T q0
#define WS_A     16       // 256    A = Wq1^T Wk1
#define WS_E0    272      // 4096   E0 = Pp0 * Wv0  (256 x 16), f32 (for c0)
#define WS_BT    4368     // 20480 f32-slots = 40960 ushort: BTall[256][160] bf16
//   BTall[d][kk]: kk 0..15 = Px[d][l]; 16..31 = E1[d][l]; 32..95 = Psin[d][j]; 96..159 = Pcos[d][j]
// total 24848 floats ~ 100 KB

typedef float f32x4 __attribute__((ext_vector_type(4)));
typedef short s16x8 __attribute__((ext_vector_type(8)));
typedef short s16x4 __attribute__((ext_vector_type(4)));

static __device__ __forceinline__ short bf16b(float f) {
  __hip_bfloat16 h = __float2bfloat16(f);
  return __builtin_bit_cast(short, h);
}

__global__ __launch_bounds__(512)
void pre_kernel(const float* __restrict__ Wq, const float* __restrict__ Wk,
                const float* __restrict__ Wv, const float* __restrict__ pw,
                float* __restrict__ ws)
{
  __shared__ float q0s[256];
  const int t = threadIdx.x;
  const int blk = blockIdx.x;
  ushort* bt = (ushort*)(ws + WS_BT);
  if (blk == 0) {
    if (t < 256) {
      float s = 0.f;
      #pragma unroll
      for (int l = 0; l < 16; ++l) s += Wq[t*16 + l];   // q0[d]
      q0s[t] = s;
    }
    __syncthreads();
    if (t < 16) {
      float s = 0.f;
      for (int d = 0; d < 256; ++d) s += q0s[d] * Wk[d*16 + t];  // wk0[l]
      ws[WS_WK0 + t] = s;
    }
    if (t < 256) {
      const int l1 = t >> 4, l2 = t & 15;
      float s = 0.f;
      for (int d = 0; d < 256; ++d)
        s += Wq[4096 + d*16 + l1] * Wk[4096 + d*16 + l2];  // A[l1,l2]
      ws[WS_A + t] = s;
    }
  } else if (blk <= 8) {
    const int d = (blk-1)*32 + (t >> 4);
    const int l = t & 15;
    float s = 0.f;
    for (int f = 0; f < 256; ++f) s += pw[d*656 + 16 + f] * Wv[f*16 + l];
    ws[WS_E0 + d*16 + l] = s;                      // E0 f32
    bt[d*160 + l] = (ushort)bf16b(pw[d*656 + l]);  // Px -> BTall kk 0..15
  } else if (blk <= 16) {
    const int d = (blk-9)*32 + (t >> 4);
    const int l = t & 15;
    float s = 0.f;
    for (int f = 0; f < 256; ++f) s += pw[d*656 + 272 + f] * Wv[4096 + f*16 + l];
    bt[d*160 + 16 + l] = (ushort)bf16b(s);         // E1 -> BTall kk 16..31
  } else {
    // sin/cos proj weights -> BTall kk 32..159
    #pragma unroll 4
    for (int k = 0; k < 64; ++k) {
      const int e = k*512 + t;          // 0..32767
      const int d = e >> 7, j = e & 127;
      const float v = (j < 64) ? pw[d*656 + 528 + j] : pw[d*656 + 592 + (j-64)];
      bt[d*160 + 32 + j] = (ushort)bf16b(v);
    }
  }
}

__global__ __launch_bounds__(256, 2)
void main_kernel(const float* __restrict__ x, const float* __restrict__ fw,
                 const float* __restrict__ fb, const float* __restrict__ pw,
                 const float* __restrict__ pb, const float* __restrict__ ws,
                 float* __restrict__ out)
{
  __shared__ float XsT[16*68];     // f32 x^T [l][c] (padded)
  __shared__ float fws[16*64];
  __shared__ float fbs[64];
  __shared__ float Gs[256];        // G = X^T X
  __shared__ float N1s[256];       // N1 = A*G
  __shared__ float tls[16];        // t = G*wk0
  __shared__ float c0s[256];       // pb[d] + sum_l t[l]*E0[d,l]
  __shared__ short Abf[20*64*8];   // bf16 A[kt][c][8]: kt0-1=x, kt2-3=M=X*N1, kt4-11=sin, kt12-19=cos

  const int t = threadIdx.x;
  const int b = blockIdx.x >> 7;
  const int p = blockIdx.x & 127;

  // ---- phase 1: stage X (f32 + bf16 kt0-1), fw, fb ----
  {
    const int c = t >> 2, l0 = (t & 3) * 4;
    const float4 v = *(const float4*)(x + (((b*64 + c)*128 + p) << 4) + l0);
    XsT[(l0+0)*68 + c] = v.x;
    XsT[(l0+1)*68 + c] = v.y;
    XsT[(l0+2)*68 + c] = v.z;
    XsT[(l0+3)*68 + c] = v.w;
    s16x4 xb;
    xb[0] = bf16b(v.x); xb[1] = bf16b(v.y); xb[2] = bf16b(v.z); xb[3] = bf16b(v.w);
    *(s16x4*)&Abf[(((l0>>3)*64 + c) << 3) + (l0 & 4)] = xb;
  }
  *(float4*)(fws + t*4) = *(const float4*)(fw + t*4);
  if (t < 16) *(float4*)(fbs + t*4) = *(const float4*)(fb + t*4);
  __syncthreads();

  // ---- phase 2: G[l1][l2]; wx + sincos -> Abf kt4..19 ----
  {
    const int l1 = t >> 4, l2 = t & 15;
    float g = 0.f;
    #pragma unroll
    for (int c = 0; c < 64; ++c) g += XsT[l1*68 + c] * XsT[l2*68 + c];
    Gs[t] = g;
  }
  {
    const int c = t & 63, jb = t >> 6;
    float sv[16], cv[16];
    #pragma unroll
    for (int k = 0; k < 16; ++k) {
      const int j = jb*16 + k;
      float wx = fbs[j];
      #pragma unroll
      for (int l = 0; l < 16; ++l) wx += XsT[l*68 + c] * fws[l*64 + j];
      __sincosf(wx, &sv[k], &cv[k]);
    }
    s16x8 pk;
    #pragma unroll
    for (int e = 0; e < 8; ++e) pk[e] = bf16b(sv[e]);
    *(s16x8*)&Abf[(((4 + 2*jb)*64 + c) << 3)] = pk;
    #pragma unroll
    for (int e = 0; e < 8; ++e) pk[e] = bf16b(sv[8+e]);
    *(s16x8*)&Abf[(((5 + 2*jb)*64 + c) << 3)] = pk;
    #pragma unroll
    for (int e = 0; e < 8; ++e) pk[e] = bf16b(cv[e]);
    *(s16x8*)&Abf[(((12 + 2*jb)*64 + c) << 3)] = pk;
    #pragma unroll
    for (int e = 0; e < 8; ++e) pk[e] = bf16b(cv[8+e]);
    *(s16x8*)&Abf[(((13 + 2*jb)*64 + c) << 3)] = pk;
  }
  __syncthreads();

  // ---- phase 3: N1 = A*G ; tls = G*wk0 ----
  {
    const int l1 = t >> 4, l2 = t & 15;
    float s = 0.f;
    #pragma unroll
    for (int k = 0; k < 16; ++k) s += ws[WS_A + l1*16 + k] * Gs[k*16 + l2];
    N1s[t] = s;
  }
  if (t < 16) {
    float s = 0.f;
    #pragma unroll
    for (int k = 0; k < 16; ++k) s += Gs[t*16 + k] * ws[WS_WK0 + k];
    tls[t] = s;
  }
  __syncthreads();

  // ---- phase 4: M = X*N1 -> Abf kt2-3 (bf16); c0[d] f32 ----
  {
    const int c = t >> 2, lp0 = (t & 3) * 4;
    float m0 = 0.f, m1 = 0.f, m2 = 0.f, m3 = 0.f;
    #pragma unroll
    for (int l = 0; l < 16; ++l) {
      const float xv = XsT[l*68 + c];
      m0 += xv * N1s[l*16 + lp0];
      m1 += xv * N1s[l*16 + lp0+1];
      m2 += xv * N1s[l*16 + lp0+2];
      m3 += xv * N1s[l*16 + lp0+3];
    }
    s16x4 mb;
    mb[0] = bf16b(m0); mb[1] = bf16b(m1); mb[2] = bf16b(m2); mb[3] = bf16b(m3);
    *(s16x4*)&Abf[(((2 + (lp0>>3))*64 + c) << 3) + (lp0 & 4)] = mb;
  }
  {
    const int d = t;
    float s = pb[d];
    #pragma unroll
    for (int l = 0; l < 16; ++l) s += tls[l] * ws[WS_E0 + d*16 + l];
    c0s[d] = s;
  }
  __syncthreads();

  // ---- phase 5: 5 uniform MFMA k-steps over K=160 ----
  const int lane = t & 63, w = t >> 6;
  const int n0 = w << 6;
  const int lr = lane & 15, lq = lane >> 4;
  f32x4 acc[4][4] = {};
  const ushort* BT = (const ushort*)(ws + WS_BT);
  #pragma unroll
  for (int ks = 0; ks < 5; ++ks) {
    s16x8 af[4], bf_[4];
    #pragma unroll
    for (int mi = 0; mi < 4; ++mi)
      af[mi] = *(const s16x8*)&Abf[(((ks*4 + lq)*64) + mi*16 + lr) << 3];
    #pragma unroll
    for (int nt = 0; nt < 4; ++nt)
      bf_[nt] = *(const s16x8*)&BT[(n0 + nt*16 + lr)*160 + ks*32 + lq*8];
    #pragma unroll
    for (int mi = 0; mi < 4; ++mi)
      #pragma unroll
      for (int nt = 0; nt < 4; ++nt)
        acc[mi][nt] = __builtin_amdgcn_mfma_f32_16x16x32_bf16(af[mi], bf_[nt], acc[mi][nt], 0, 0, 0);
  }

  // ---- epilogue: + c0[d], store ----
  #pragma unroll
  for (int nt = 0; nt < 4; ++nt) {
    const int d = n0 + nt*16 + lr;
    const float cc = c0s[d];
    #pragma unroll
    for (int mi = 0; mi < 4; ++mi) {
      #pragma unroll
      for (int r = 0; r < 4; ++r) {
        const int c = mi*16 + lq*4 + r;
        out[(((b*64 + c)*128 + p) << 8) + d] = acc[mi][nt][r] + cc;
      }
    }
  }
}

extern "C" void kernel_launch(void* const* d_in, const int* in_sizes, int n_in,
                              void* d_out, int out_size, void* d_ws, size_t ws_size,
                              hipStream_t stream) {
  const float* x  = (const float*)d_in[0];
  const float* Wq = (const float*)d_in[1];
  const float* Wk = (const float*)d_in[2];
  const float* Wv = (const float*)d_in[3];
  const float* fw = (const float*)d_in[4];
  const float* fb = (const float*)d_in[5];
  const float* pw = (const float*)d_in[6];
  const float* pb = (const float*)d_in[7];
  float* out = (float*)d_out;
  float* ws  = (float*)d_ws;   // needs 24848 floats ~ 100 KB

  pre_kernel<<<18, 512, 0, stream>>>(Wq, Wk, Wv, pw, ws);
  main_kernel<<<16*128, 256, 0, stream>>>(x, fw, fb, pw, pb, ws, out);
}